// Round 14
// baseline (196.862 us; speedup 1.0000x reference)
//
#include <hip/hip_runtime.h>
#include <hip/hip_bf16.h>
#include <math.h>

// Problem constants
#define T_ 4
#define N_ 16
#define F_ 6
#define L_ 1024
#define A_ 21
#define K_ 20
#define U_ 256
#define LOUT 1005            // L - K + 1
#define NIMG 384             // T*N*F
#define SZ_S (T_*N_*U_)      // 16384
#define SZ_R (K_*A_*U_)      // 107520

// Packed-X geometry: row stride 24 shorts (48 B). For output row l, contraction
// slot c maps to tap=c/24, col=c%24 (independent of l). Valid slots 0..476 ->
// 15 blocks of 32 slots (480); cols 21..23 zero in R.
#define XPR 24               // shorts per packed row
#define XROWS 1056           // padded rows per image
#define NSTEP 15             // 32-slot K-blocks
#define XCHUNKS 14           // X LDS chunks of 1 KB

// Rt layout (fragment-ordered for conflict-free 32x32x16 LDS reads):
// Rt[b][H][c][unit][j]: b=32-slot block (15), H=u>>6 (4 64-u halves),
// c=ut*2+h (ut=(u>>5)&1, h=(s&31)>>4), unit=(u&31)*2+((s>>3)&1), j=s&7.
// Shorts: off = b*8192 + H*2048 + c*512 + unit*8 + j.  Total 240 KB.

typedef __attribute__((ext_vector_type(8))) short short8;    // 8 bf16
typedef __attribute__((ext_vector_type(4))) float f32x4;
typedef __attribute__((ext_vector_type(16))) float f32x16;   // 32x32 acc

__device__ __forceinline__ unsigned short f2bf(float f) {
  unsigned int u = __float_as_uint(f);
  u += 0x7FFFu + ((u >> 16) & 1u);   // round to nearest even
  return (unsigned short)(u >> 16);
}

__device__ __forceinline__ void atomicMaxF(float* addr, float val) {
  if (val >= 0.f) atomicMax((int*)addr, __float_as_int(val));
  else            atomicMin((unsigned int*)addr, __float_as_uint(val));
}

// Async global->LDS, 16B per lane. LDS dest is wave-uniform base + lane*16.
__device__ __forceinline__ void gload_lds16(const void* g, void* l) {
  __builtin_amdgcn_global_load_lds(
      (const __attribute__((address_space(1))) void*)g,
      (__attribute__((address_space(3))) void*)l, 16, 0, 0);
}

// Merged pre-pass: S init, R (fp32 exact) -> d_out, Rt (fragment-ordered bf16),
// X fp32 -> packed bf16 Xp. One launch.
__global__ void xprep_kernel(const float* __restrict__ X,
                             const float* __restrict__ P_logit,
                             const float* __restrict__ Q,
                             float* __restrict__ out,
                             unsigned short* __restrict__ Rt,
                             unsigned int* __restrict__ Xp32) {
  int t = blockIdx.x * blockDim.x + threadIdx.x;
  if (t < SZ_S) out[t] = -INFINITY;            // S init for atomic max

  if (t < K_ * U_) {                           // R / Rt part
    int k = t / U_;
    int u = t - k * U_;
    const float* pl = P_logit + (size_t)k * A_ * U_ + u;
    float v[A_];
    float m = -INFINITY;
#pragma unroll
    for (int a = 0; a < A_; ++a) { v[a] = pl[(size_t)a * U_]; m = fmaxf(m, v[a]); }
    float s = 0.f;
#pragma unroll
    for (int a = 0; a < A_; ++a) { v[a] = expf(v[a] - m); s += v[a]; }
    float qs = 0.f;
#pragma unroll
    for (int a = 0; a < A_; ++a) qs += Q[a];
    float eps = qs * (1.0f / A_);
    float invs = 1.f / s;
    float* Rout = out + SZ_S;
    const int H  = u >> 6;
    const int ut = (u >> 5) & 1;
    const int r  = u & 31;
#pragma unroll
    for (int a = 0; a < XPR; ++a) {
      float rv = 0.f;
      if (a < A_) {
        rv = logf(fmaxf(v[a] * invs / Q[a], eps));
        Rout[(size_t)(k * A_ + a) * U_ + u] = rv;
      }
      int sl = k * XPR + a;
      int b = sl >> 5, s5 = sl & 31;
      int h = s5 >> 4, q = (s5 >> 3) & 1, j = s5 & 7;
      Rt[(size_t)b * 8192 + H * 2048 + (ut * 2 + h) * 512 + (r * 2 + q) * 8 + j]
          = (a < A_) ? f2bf(rv) : 0;
    }
  }

  if (t < NIMG * XROWS * 12) {                 // X conversion part
    int w  = t % 12;
    int rl = t / 12;               // n*XROWS + row
    int row = rl % XROWS;
    int n   = rl / XROWS;
    int c0 = w * 2;
    float v0 = 0.f, v1 = 0.f;
    if (row < L_) {
      const float* xr = X + ((size_t)n * L_ + row) * A_;
      if (c0 < A_)     v0 = xr[c0];
      if (c0 + 1 < A_) v1 = xr[c0 + 1];
    }
    unsigned int o = (unsigned int)f2bf(v0) | ((unsigned int)f2bf(v1) << 16);
    Xp32[(size_t)rl * 12 + w] = o;
  }
}

// Conv as one GEMM: M=u (A=R), N=l (B=packed-X), K=480 (15 x 32-slot blocks,
// each = 2 x 32x32x16 MFMA K-halves). Barrier-free K-loop (R13 structure):
// per-wave private 16 KB R ring (4 slots x 4 KB = its 64-u half), staged via
// global_load_lds, certified by per-wave counted vmcnt; X staged once (one
// prologue barrier). Register-carried frags (read k+1 under MFMA k).
// 32x32x16 frag maps (R7-verified): A/B row/col = lane&31, k=(lane>>5)*8+j;
// C/D col=lane&31, row=(reg&3)+8*(reg>>2)+4*(lane>>5).
// R LDS reads are CONTIGUOUS 1 KB per fragment (fragment-ordered Rt) -> zero
// bank conflicts. Block 128u x 256l, wave 64u x 128l (2x4 32x32 frags).
__global__ __launch_bounds__(256, 2) void conv_kernel(
    const unsigned short* __restrict__ Xp,
    const unsigned short* __restrict__ Rt,
    float* __restrict__ out) {
  __shared__ __align__(16) unsigned short lds_x[XCHUNKS * 512];   // 14 KB
  __shared__ __align__(16) unsigned short lds_r[4][4][2048];      // 64 KB

  const int n  = blockIdx.z;
  const int l0 = blockIdx.y * 256;
  const int u0 = blockIdx.x * 128;
  const int wid  = threadIdx.x >> 6;
  const int lane = threadIdx.x & 63;
  const int wl = wid >> 1;             // wave l position (0..1), 128 l each
  const int wu = wid & 1;              // wave u position (0..1), 64 u each

  const char* xsrc = (const char*)Xp + ((size_t)n * XROWS + l0) * (XPR * 2);
  // wave's private R source: its 4 KB H-half of each 16 KB step-block
  const int H = (u0 >> 6) + wu;
  const char* rsrc = (const char*)Rt + (size_t)H * 4096;
  char* rdst = (char*)&lds_r[wid][0][0];

#define STAGE(KK)                                                            \
  {                                                                          \
    _Pragma("unroll")                                                        \
    for (int c = 0; c < 4; ++c)                                              \
      gload_lds16(rsrc + (size_t)(KK) * 16384 + c * 1024 + lane * 16,        \
                  rdst + ((KK) & 3) * 4096 + c * 1024);                      \
  }

  // ---- prologue: X (3-4 chunks/wave, shared) + private R steps 0..2
  for (int c = wid; c < XCHUNKS; c += 4)
    gload_lds16(xsrc + c * 1024 + lane * 16, (char*)lds_x + c * 1024);
  STAGE(0) STAGE(1) STAGE(2)
  asm volatile("s_waitcnt vmcnt(12)" ::: "memory");
  __builtin_amdgcn_s_barrier();        // the ONLY barrier: X visible to all

  const int r32 = lane & 31;           // frag row (A: u) / col (B: l)
  const int hi  = lane >> 5;           // k sub-chunk (8 shorts)

  f32x16 acc[2][4];                    // [ut][lt] = 128 regs
#pragma unroll
  for (int ut = 0; ut < 2; ++ut)
#pragma unroll
    for (int lt = 0; lt < 4; ++lt)
#pragma unroll
      for (int i = 0; i < 16; ++i) acc[ut][lt][i] = 0.f;

  // X frag(kk, lt, h): xb + lt*(32*XPR) + kk*32 + h*16 (shorts)
  const unsigned short* xb = lds_x + (wl * 128 + r32) * XPR + hi * 8;
  // R frag(kk, ut, h): contiguous 1 KB: rbw + (kk&3)*2048 + (ut*2+h)*512
  const unsigned short* rbw =
      (const unsigned short*)rdst + r32 * 16 + hi * 8;

#define READ_FRAGS(KK, X8, R8)                                               \
  {                                                                          \
    _Pragma("unroll")                                                        \
    for (int lt = 0; lt < 4; ++lt)                                           \
      _Pragma("unroll")                                                      \
      for (int h = 0; h < 2; ++h)                                            \
        (X8)[lt][h] =                                                        \
            *(const short8*)(xb + lt * (32 * XPR) + (KK) * 32 + h * 16);     \
    _Pragma("unroll")                                                        \
    for (int ut = 0; ut < 2; ++ut)                                           \
      _Pragma("unroll")                                                      \
      for (int h = 0; h < 2; ++h)                                            \
        (R8)[ut][h] = *(const short8*)(rbw + ((KK) & 3) * 2048 +             \
                                       (ut * 2 + h) * 512);                  \
  }

#define MFMA16(R8, X8)                                                       \
  {                                                                          \
    __builtin_amdgcn_s_setprio(1);                                           \
    _Pragma("unroll")                                                        \
    for (int h = 0; h < 2; ++h)                                              \
      _Pragma("unroll")                                                      \
      for (int ut = 0; ut < 2; ++ut)                                         \
        _Pragma("unroll")                                                    \
        for (int lt = 0; lt < 4; ++lt)                                       \
          acc[ut][lt] = __builtin_amdgcn_mfma_f32_32x32x16_bf16(             \
              (R8)[ut][h], (X8)[lt][h], acc[ut][lt], 0, 0, 0);               \
    __builtin_amdgcn_s_setprio(0);                                           \
  }

  short8 fx[2][4][2], fr[2][2][2];     // ping-pong carried fragments
  // certify private step 0 (steps 1,2 = 8 loads may remain in flight)
  asm volatile("s_waitcnt vmcnt(8)" ::: "memory");
  READ_FRAGS(0, fx[0], fr[0])

#pragma unroll
  for (int k = 0; k < NSTEP; ++k) {
    const int cb = k & 1, nb = cb ^ 1;
    if (k + 3 < NSTEP) STAGE(k + 3)
    if (k + 1 < NSTEP) {
      if (k <= NSTEP - 4)      asm volatile("s_waitcnt vmcnt(8)" ::: "memory");
      else if (k == NSTEP - 3) asm volatile("s_waitcnt vmcnt(4)" ::: "memory");
      else                     asm volatile("s_waitcnt vmcnt(0)" ::: "memory");
      READ_FRAGS(k + 1, fx[nb], fr[nb])
    }
    MFMA16(fr[cb], fx[cb])
  }

#undef READ_FRAGS
#undef MFMA16
#undef STAGE

  // Epilogue (R7-verified 32x32 C/D map): lane holds col l = ...+r32 fixed;
  // rows u = ut*32 + 8*rq + 4*hi + (0..3) per f32x4 quad -> 16 B stores.
  float* Z = out + SZ_S + SZ_R;
  f32x4 pm[2][4];                      // [ut][rq]
#pragma unroll
  for (int ut = 0; ut < 2; ++ut)
#pragma unroll
    for (int rq = 0; rq < 4; ++rq)
#pragma unroll
      for (int j = 0; j < 4; ++j) pm[ut][rq][j] = -INFINITY;

#pragma unroll
  for (int lt = 0; lt < 4; ++lt) {
    const int l = l0 + wl * 128 + lt * 32 + r32;
    if (l < LOUT) {
#pragma unroll
      for (int ut = 0; ut < 2; ++ut) {
        float* zrow = Z + ((size_t)n * LOUT + l) * U_ + u0 + wu * 64 +
                      ut * 32 + hi * 4;
#pragma unroll
        for (int rq = 0; rq < 4; ++rq) {
          f32x4 v;
#pragma unroll
          for (int j = 0; j < 4; ++j) v[j] = acc[ut][lt][4 * rq + j];
          *(f32x4*)(zrow + 8 * rq) = v;
#pragma unroll
          for (int j = 0; j < 4; ++j) pm[ut][rq][j] = fmaxf(pm[ut][rq][j], v[j]);
        }
      }
    }
  }

  // Max over the frag's 32 cols (l): xor-reduce within lane&31 (hi preserved).
#pragma unroll
  for (int off = 1; off < 32; off <<= 1)
#pragma unroll
    for (int ut = 0; ut < 2; ++ut)
#pragma unroll
      for (int rq = 0; rq < 4; ++rq)
#pragma unroll
        for (int j = 0; j < 4; ++j)
          pm[ut][rq][j] = fmaxf(pm[ut][rq][j], __shfl_xor(pm[ut][rq][j], off));

  if (r32 == 0) {                      // lanes 0 and 32 (hi = 0/1)
    const int tn = n / F_;
    float* Sp = out + (size_t)tn * U_ + u0 + wu * 64 + hi * 4;
#pragma unroll
    for (int ut = 0; ut < 2; ++ut)
#pragma unroll
      for (int rq = 0; rq < 4; ++rq)
#pragma unroll
        for (int j = 0; j < 4; ++j)
          atomicMaxF(Sp + ut * 32 + 8 * rq + j, pm[ut][rq][j]);
  }
}

extern "C" void kernel_launch(void* const* d_in, const int* in_sizes, int n_in,
                              void* d_out, int out_size, void* d_ws, size_t ws_size,
                              hipStream_t stream) {
  const float* X       = (const float*)d_in[0];
  const float* P_logit = (const float*)d_in[1];
  const float* Q       = (const float*)d_in[2];
  float* out = (float*)d_out;

  unsigned short* Rt = (unsigned short*)d_ws;            // 240 KB
  unsigned short* Xp = (unsigned short*)((char*)d_ws + 262144);
  // Xp: NIMG*XROWS*24 shorts (~18.6 MB) + slack inside region for the last
  // block's LDS stage over-read (staged-but-never-consumed rows).

  int xthreads = NIMG * XROWS * 12;
  hipLaunchKernelGGL(xprep_kernel, dim3((xthreads + 255) / 256), dim3(256),
                     0, stream, X, P_logit, Q, out, Rt, (unsigned int*)Xp);
  dim3 grid(2, 4, NIMG);   // u-tiles, l-tiles (256 each), images
  hipLaunchKernelGGL(conv_kernel, grid, dim3(256), 0, stream, Xp, Rt, out);
}

// Round 15
// 160.875 us; speedup vs baseline: 1.2237x; 1.2237x over previous
//
#include <hip/hip_runtime.h>
#include <hip/hip_bf16.h>
#include <math.h>

// Problem constants
#define T_ 4
#define N_ 16
#define F_ 6
#define L_ 1024
#define A_ 21
#define K_ 20
#define U_ 256
#define LOUT 1005            // L - K + 1
#define NIMG 384             // T*N*F
#define SZ_S (T_*N_*U_)      // 16384
#define SZ_R (K_*A_*U_)      // 107520

// Packed-X geometry: row stride 24 shorts (48 B). For output row l, contraction
// slot c maps to tap=c/24, col=c%24 (independent of l). Valid slots 0..476 ->
// 15 K-steps of 32 (480); cols 21..23 zero in R.
#define XPR 24               // shorts per packed row
#define XROWS 1056           // padded rows per image
#define NSTEP 15             // K-steps of 32 slots
#define XCHUNKS 10           // X LDS chunks of 1 KB (213 rows >= 211 needed)

typedef __attribute__((ext_vector_type(8))) short short8;   // 8 bf16 (4 VGPR)
typedef __attribute__((ext_vector_type(4))) float f32x4;    // 4 f32 acc

__device__ __forceinline__ unsigned short f2bf(float f) {
  unsigned int u = __float_as_uint(f);
  u += 0x7FFFu + ((u >> 16) & 1u);   // round to nearest even
  return (unsigned short)(u >> 16);
}

__device__ __forceinline__ void atomicMaxF(float* addr, float val) {
  if (val >= 0.f) atomicMax((int*)addr, __float_as_int(val));
  else            atomicMin((unsigned int*)addr, __float_as_uint(val));
}

// Async global->LDS, 16B per lane. LDS dest is wave-uniform base + lane*16.
__device__ __forceinline__ void gload_lds16(const void* g, void* l) {
  __builtin_amdgcn_global_load_lds(
      (const __attribute__((address_space(1))) void*)g,
      (__attribute__((address_space(3))) void*)l, 16, 0, 0);
}

// Merged pre-pass (single launch): S init, R (fp32 exact) -> d_out,
// Rt = bf16 R in slot order Rt[(s>>5)*(U*32) + u*32 + (s&31)] (pads zeroed),
// X fp32 -> packed bf16 Xp.
__global__ void xprep_kernel(const float* __restrict__ X,
                             const float* __restrict__ P_logit,
                             const float* __restrict__ Q,
                             float* __restrict__ out,
                             unsigned short* __restrict__ Rt,
                             unsigned int* __restrict__ Xp32) {
  int t = blockIdx.x * blockDim.x + threadIdx.x;
  if (t < SZ_S) out[t] = -INFINITY;            // S init for atomic max

  if (t < K_ * U_) {                           // R / Rt part
    int k = t / U_;
    int u = t - k * U_;
    const float* pl = P_logit + (size_t)k * A_ * U_ + u;
    float v[A_];
    float m = -INFINITY;
#pragma unroll
    for (int a = 0; a < A_; ++a) { v[a] = pl[(size_t)a * U_]; m = fmaxf(m, v[a]); }
    float s = 0.f;
#pragma unroll
    for (int a = 0; a < A_; ++a) { v[a] = expf(v[a] - m); s += v[a]; }
    float qs = 0.f;
#pragma unroll
    for (int a = 0; a < A_; ++a) qs += Q[a];
    float eps = qs * (1.0f / A_);
    float invs = 1.f / s;
    float* Rout = out + SZ_S;
#pragma unroll
    for (int a = 0; a < XPR; ++a) {
      unsigned short bv = 0;
      if (a < A_) {
        float r = logf(fmaxf(v[a] * invs / Q[a], eps));
        Rout[(size_t)(k * A_ + a) * U_ + u] = r;
        bv = f2bf(r);
      }
      int sl = k * XPR + a;
      Rt[(size_t)(sl >> 5) * (U_ * 32) + u * 32 + (sl & 31)] = bv;
    }
  }

  if (t < NIMG * XROWS * 12) {                 // X conversion part
    int w  = t % 12;
    int rl = t / 12;               // n*XROWS + row
    int row = rl % XROWS;
    int n   = rl / XROWS;
    int c0 = w * 2;
    float v0 = 0.f, v1 = 0.f;
    if (row < L_) {
      const float* xr = X + ((size_t)n * L_ + row) * A_;
      if (c0 < A_)     v0 = xr[c0];
      if (c0 + 1 < A_) v1 = xr[c0 + 1];
    }
    unsigned int o = (unsigned int)f2bf(v0) | ((unsigned int)f2bf(v1) << 16);
    Xp32[(size_t)rl * 12 + w] = o;
  }
}

// Conv as one GEMM: M=u (A=R slots), N=l (B=packed-X window), K=480 (15 steps).
// R15 change vs R13 (best, 148 µs): 3 blocks/CU. Wave tile 64u x 96l (4x6
// frags, 24 MFMA/step, acc=96 VGPR), private R ring shrunk to 2 slots (8 KB/
// wave), no reg-carry: iter k = { STAGE(k+1) -> vmcnt(4) (certifies step k,
// staged one full iteration earlier) -> read frags k -> MFMA }. LDS = 10 KB X
// + 32 KB R = 42 KB -> 3 blocks/CU at 3 waves/SIMD (VGPR <= 168). Barrier-free
// K-loop, per-wave counted vmcnt (R13-proven). Block 128u x 192l.
__global__ __launch_bounds__(256, 3) void conv_kernel(
    const unsigned short* __restrict__ Xp,
    const unsigned short* __restrict__ Rt,
    float* __restrict__ out) {
  __shared__ __align__(16) unsigned short lds_x[XCHUNKS * 512];   // 10 KB
  __shared__ __align__(16) unsigned short lds_r[4][2][2048];      // 32 KB

  const int n  = blockIdx.z;
  const int l0 = blockIdx.y * 192;
  const int u0 = blockIdx.x * 128;
  const int wid  = threadIdx.x >> 6;
  const int lane = threadIdx.x & 63;
  const int wl = wid >> 1;             // wave l position (0..1), 96 l each
  const int wu = wid & 1;              // wave u position (0..1), 64 u each

  const char* xsrc = (const char*)Xp + ((size_t)n * XROWS + l0) * (XPR * 2);
  // wave's private R source: its wu-half (4 KB) of each 16 KB step
  const char* rsrc = (const char*)Rt + (size_t)u0 * 64 + wu * 4096;
  char* rdst = (char*)&lds_r[wid][0][0];

#define STAGE(KK)                                                            \
  {                                                                          \
    _Pragma("unroll")                                                        \
    for (int c = 0; c < 4; ++c)                                              \
      gload_lds16(rsrc + (size_t)(KK) * (U_ * 64) + c * 1024 + lane * 16,    \
                  rdst + ((KK) & 1) * 4096 + c * 1024);                      \
  }

  // ---- prologue: X (2-3 chunks/wave, shared) + private R step 0
  for (int c = wid; c < XCHUNKS; c += 4)
    gload_lds16(xsrc + c * 1024 + lane * 16, (char*)lds_x + c * 1024);
  STAGE(0)
  asm volatile("s_waitcnt vmcnt(0)" ::: "memory");
  __builtin_amdgcn_s_barrier();        // the ONLY barrier: X visible to all

  const int fl = lane & 15;            // frag row (A: u) / col (B: l)
  const int fj = lane >> 4;            // k sub-chunk (8 shorts each)

  f32x4 acc[4][6];                     // [ut][lt] = 96 VGPR
#pragma unroll
  for (int ut = 0; ut < 4; ++ut)
#pragma unroll
    for (int lt = 0; lt < 6; ++lt)
      acc[ut][lt] = (f32x4){0.f, 0.f, 0.f, 0.f};

  // X frag(kk, lt): row (wl*96 + lt*16 + fl), shorts row*24 + kk*32 + fj*8
  const unsigned short* xb = lds_x + (wl * 96 + fl) * XPR + (fj << 3);
  // R frag(kk, ut): private slot kk&1, row (ut*16 + fl) of the 64-row half
  const unsigned short* rbw =
      (const unsigned short*)rdst + fl * 32 + (fj << 3);

#pragma unroll 1
  for (int k = 0; k < NSTEP; ++k) {
    // stage next step into the other slot; certify THIS step (issued one full
    // iteration ago -> ~600 cyc latency cover), per-wave counter, no barrier.
    if (k + 1 < NSTEP) {
      STAGE(k + 1)
      asm volatile("s_waitcnt vmcnt(4)" ::: "memory");
    } else {
      asm volatile("s_waitcnt vmcnt(0)" ::: "memory");
    }
    short8 xfr[6], rfr[4];
    const unsigned short* rb = rbw + (k & 1) * 2048;
#pragma unroll
    for (int lt = 0; lt < 6; ++lt)
      xfr[lt] = *(const short8*)(xb + lt * (16 * XPR) + k * 32);
#pragma unroll
    for (int ut = 0; ut < 4; ++ut)
      rfr[ut] = *(const short8*)(rb + ut * (16 * 32));
    __builtin_amdgcn_s_setprio(1);
#pragma unroll
    for (int ut = 0; ut < 4; ++ut)
#pragma unroll
      for (int lt = 0; lt < 6; ++lt)
        acc[ut][lt] = __builtin_amdgcn_mfma_f32_16x16x32_bf16(
            rfr[ut], xfr[lt], acc[ut][lt], 0, 0, 0);
    __builtin_amdgcn_s_setprio(0);
  }

#undef STAGE

  // Epilogue: D layout col(l)=lane&15, row(u)=(lane>>4)*4+reg -> lane holds
  // 4 consecutive u at fixed l => float4 store into row-major Z[l][u].
  float* Z = out + SZ_S + SZ_R;
  const int ug = fj << 2;
  float pmax[4][4];                    // [ut][reg]
#pragma unroll
  for (int ut = 0; ut < 4; ++ut)
#pragma unroll
    for (int r = 0; r < 4; ++r) pmax[ut][r] = -INFINITY;

#pragma unroll
  for (int lt = 0; lt < 6; ++lt) {
    const int l = l0 + wl * 96 + lt * 16 + fl;
    if (l < LOUT) {
      float* zrow = Z + ((size_t)n * LOUT + l) * U_ + u0 + wu * 64 + ug;
#pragma unroll
      for (int ut = 0; ut < 4; ++ut) {
        f32x4 v = acc[ut][lt];
        *(f32x4*)(zrow + ut * 16) = v;
#pragma unroll
        for (int r = 0; r < 4; ++r) pmax[ut][r] = fmaxf(pmax[ut][r], v[r]);
      }
    }
  }

  // Max over the frag's 16 cols (l): xor-reduce over lane&15 (fj preserved).
#pragma unroll
  for (int off = 1; off < 16; off <<= 1)
#pragma unroll
    for (int ut = 0; ut < 4; ++ut)
#pragma unroll
      for (int r = 0; r < 4; ++r)
        pmax[ut][r] = fmaxf(pmax[ut][r], __shfl_xor(pmax[ut][r], off));

  if (fl == 0) {                       // lanes fj*16
    const int tn = n / F_;
    float* Sp = out + (size_t)tn * U_ + u0 + wu * 64 + ug;
#pragma unroll
    for (int ut = 0; ut < 4; ++ut)
#pragma unroll
      for (int r = 0; r < 4; ++r)
        atomicMaxF(Sp + ut * 16 + r, pmax[ut][r]);
  }
}

extern "C" void kernel_launch(void* const* d_in, const int* in_sizes, int n_in,
                              void* d_out, int out_size, void* d_ws, size_t ws_size,
                              hipStream_t stream) {
  const float* X       = (const float*)d_in[0];
  const float* P_logit = (const float*)d_in[1];
  const float* Q       = (const float*)d_in[2];
  float* out = (float*)d_out;

  unsigned short* Rt = (unsigned short*)d_ws;            // 240 KB
  unsigned short* Xp = (unsigned short*)((char*)d_ws + 262144);
  // Xp: NIMG*XROWS*24 shorts (~18.6 MB). The last l-tile (l0=960) over-reads
  // <= 5.6 KB past Xp into ws slack (0xAA poison = finite bf16; rows guarded
  // by l < LOUT in the epilogue, so values never reach the output).

  int xthreads = NIMG * XROWS * 12;
  hipLaunchKernelGGL(xprep_kernel, dim3((xthreads + 255) / 256), dim3(256),
                     0, stream, X, P_logit, Q, out, Rt, (unsigned int*)Xp);
  dim3 grid(2, 6, NIMG);   // u-tiles, l-tiles (192 each), images
  hipLaunchKernelGGL(conv_kernel, grid, dim3(256), 0, stream, Xp, Rt, out);
}

// Round 16
// 141.287 us; speedup vs baseline: 1.3933x; 1.1386x over previous
//
#include <hip/hip_runtime.h>
#include <hip/hip_bf16.h>
#include <math.h>

// Problem constants
#define T_ 4
#define N_ 16
#define F_ 6
#define L_ 1024
#define A_ 21
#define K_ 20
#define U_ 256
#define LOUT 1005            // L - K + 1
#define NIMG 384             // T*N*F
#define SZ_S (T_*N_*U_)      // 16384
#define SZ_R (K_*A_*U_)      // 107520

// Packed-X geometry: row stride 24 shorts (48 B). For output row l, contraction
// slot c maps to tap=c/24, col=c%24 (independent of l). Valid slots 0..476 ->
// 15 K-steps of 32 (480); cols 21..23 zero in R.
#define XPR 24               // shorts per packed row
#define XROWS 1056           // padded rows per image
#define NSTEP 15             // K-steps of 32 slots
#define XCH 14               // X LDS chunks of 1 KB per tile buffer (298 rows)

typedef __attribute__((ext_vector_type(8))) short short8;   // 8 bf16 (4 VGPR)
typedef __attribute__((ext_vector_type(4))) float f32x4;    // 4 f32 acc

__device__ __forceinline__ unsigned short f2bf(float f) {
  unsigned int u = __float_as_uint(f);
  u += 0x7FFFu + ((u >> 16) & 1u);   // round to nearest even
  return (unsigned short)(u >> 16);
}

__device__ __forceinline__ void atomicMaxF(float* addr, float val) {
  if (val >= 0.f) atomicMax((int*)addr, __float_as_int(val));
  else            atomicMin((unsigned int*)addr, __float_as_uint(val));
}

// Async global->LDS, 16B per lane. LDS dest is wave-uniform base + lane*16.
__device__ __forceinline__ void gload_lds16(const void* g, void* l) {
  __builtin_amdgcn_global_load_lds(
      (const __attribute__((address_space(1))) void*)g,
      (__attribute__((address_space(3))) void*)l, 16, 0, 0);
}

// Merged pre-pass (single launch): S init, R (fp32 exact) -> d_out,
// Rt = bf16 R in slot order Rt[(s>>5)*(U*32) + u*32 + (s&31)] (pads zeroed),
// X fp32 -> packed bf16 Xp.
__global__ void xprep_kernel(const float* __restrict__ X,
                             const float* __restrict__ P_logit,
                             const float* __restrict__ Q,
                             float* __restrict__ out,
                             unsigned short* __restrict__ Rt,
                             unsigned int* __restrict__ Xp32) {
  int t = blockIdx.x * blockDim.x + threadIdx.x;
  if (t < SZ_S) out[t] = -INFINITY;            // S init for atomic max

  if (t < K_ * U_) {                           // R / Rt part
    int k = t / U_;
    int u = t - k * U_;
    const float* pl = P_logit + (size_t)k * A_ * U_ + u;
    float v[A_];
    float m = -INFINITY;
#pragma unroll
    for (int a = 0; a < A_; ++a) { v[a] = pl[(size_t)a * U_]; m = fmaxf(m, v[a]); }
    float s = 0.f;
#pragma unroll
    for (int a = 0; a < A_; ++a) { v[a] = expf(v[a] - m); s += v[a]; }
    float qs = 0.f;
#pragma unroll
    for (int a = 0; a < A_; ++a) qs += Q[a];
    float eps = qs * (1.0f / A_);
    float invs = 1.f / s;
    float* Rout = out + SZ_S;
#pragma unroll
    for (int a = 0; a < XPR; ++a) {
      unsigned short bv = 0;
      if (a < A_) {
        float r = logf(fmaxf(v[a] * invs / Q[a], eps));
        Rout[(size_t)(k * A_ + a) * U_ + u] = r;
        bv = f2bf(r);
      }
      int sl = k * XPR + a;
      Rt[(size_t)(sl >> 5) * (U_ * 32) + u * 32 + (sl & 31)] = bv;
    }
  }

  if (t < NIMG * XROWS * 12) {                 // X conversion part
    int w  = t % 12;
    int rl = t / 12;               // n*XROWS + row
    int row = rl % XROWS;
    int n   = rl / XROWS;
    int c0 = w * 2;
    float v0 = 0.f, v1 = 0.f;
    if (row < L_) {
      const float* xr = X + ((size_t)n * L_ + row) * A_;
      if (c0 < A_)     v0 = xr[c0];
      if (c0 + 1 < A_) v1 = xr[c0 + 1];
    }
    unsigned int o = (unsigned int)f2bf(v0) | ((unsigned int)f2bf(v1) << 16);
    Xp32[(size_t)rl * 12 + w] = o;
  }
}

// Conv as one GEMM: M=u (A=R slots), N=l (B=packed-X window), K=480 (15 steps).
// R16 (persistent-R): block = 128u x ALL l (4 tiles of 256), 1 block/CU
// (148 KB LDS). R staged ONCE (120 KB) in the prologue; per tile the K-loop
// is pure {12 ds_read + 32 MFMA} x 15 with ZERO vmcnt/barriers (compiler
// pipelines freely). Then: stage X(t+1) into the other buffer, issue Z stores
// fire-and-forget, vmcnt(32) (certifies stage only -- stores stay in flight
// and drain under tile t+1's K-loop), one barrier. S-max kept in registers
// across tiles, atomics once at block end. 4 waves (2u x 2l), wave 64u x 128l.
__global__ __launch_bounds__(256, 1) void conv_kernel(
    const unsigned short* __restrict__ Xp,
    const unsigned short* __restrict__ Rt,
    float* __restrict__ out) {
  __shared__ __align__(16) unsigned short lds_r[NSTEP * 4096];   // 120 KB
  __shared__ __align__(16) unsigned short lds_x[2][XCH * 512];   // 28 KB

  const int n  = blockIdx.z;
  const int u0 = blockIdx.x * 128;
  const int wid  = threadIdx.x >> 6;
  const int lane = threadIdx.x & 63;
  const int wl = wid >> 1;             // wave l position (0..1), 128 l each
  const int wu = wid & 1;              // wave u position (0..1), 64 u each

  const char* xsrc = (const char*)Xp + (size_t)n * XROWS * (XPR * 2);
  const char* rsrc = (const char*)Rt + (size_t)u0 * 64;   // block's u-half

  // ---- prologue: ALL of R (30 chunks/wave) + X tile 0 (3-4 chunks/wave)
  for (int c = wid; c < NSTEP * 8; c += 4)
    gload_lds16(rsrc + (size_t)(c >> 3) * (U_ * 64) + (c & 7) * 1024 + lane * 16,
                (char*)lds_r + c * 1024);
  for (int c = wid; c < XCH; c += 4)
    gload_lds16(xsrc + c * 1024 + lane * 16, (char*)lds_x[0] + c * 1024);
  asm volatile("s_waitcnt vmcnt(0)" ::: "memory");
  __builtin_amdgcn_s_barrier();

  const int fl = lane & 15;            // frag row (A: u) / col (B: l)
  const int fj = lane >> 4;            // k sub-chunk (8 shorts each)
  // R frag(kk, ut): lds_r + kk*4096 + (wu*64 + ut*16 + fl)*32 + fj*8
  const int rfo = (wu * 64 + fl) * 32 + (fj << 3);
  const int xro = (wl * 128 + fl) * XPR + (fj << 3);
  const int ug = fj << 2;

  float* Z = out + SZ_S + SZ_R;
  float pmax[4][4];                    // [ut][reg], carried across all tiles
#pragma unroll
  for (int ut = 0; ut < 4; ++ut)
#pragma unroll
    for (int r = 0; r < 4; ++r) pmax[ut][r] = -INFINITY;

#pragma unroll 1
  for (int t = 0; t < 4; ++t) {
    const unsigned short* xb = lds_x[t & 1] + xro;

    f32x4 acc[4][8];                   // [ut][lt]
#pragma unroll
    for (int ut = 0; ut < 4; ++ut)
#pragma unroll
      for (int lt = 0; lt < 8; ++lt)
        acc[ut][lt] = (f32x4){0.f, 0.f, 0.f, 0.f};

    // ---- K-loop: no sync of any kind; compiler software-pipelines.
#pragma unroll
    for (int k = 0; k < NSTEP; ++k) {
      short8 xfr[8], rfr[4];
      const unsigned short* rb = lds_r + k * 4096 + rfo;
#pragma unroll
      for (int lt = 0; lt < 8; ++lt)
        xfr[lt] = *(const short8*)(xb + lt * (16 * XPR) + k * 32);
#pragma unroll
      for (int ut = 0; ut < 4; ++ut)
        rfr[ut] = *(const short8*)(rb + ut * (16 * 32));
#pragma unroll
      for (int ut = 0; ut < 4; ++ut)
#pragma unroll
        for (int lt = 0; lt < 8; ++lt)
          acc[ut][lt] = __builtin_amdgcn_mfma_f32_16x16x32_bf16(
              rfr[ut], xfr[lt], acc[ut][lt], 0, 0, 0);
    }

    // ---- stage X for tile t+1 (other buffer; last read finished at the
    // barrier ending tile t-1, so overwrite is safe)
    if (t < 3) {
      const char* xs = xsrc + (size_t)(t + 1) * (256 * XPR * 2);
      for (int c = wid; c < XCH; c += 4)
        gload_lds16(xs + c * 1024 + lane * 16, (char*)lds_x[(t + 1) & 1] + c * 1024);
    }

    // ---- Z stores (fire-and-forget; drain under tile t+1's K-loop)
#pragma unroll
    for (int lt = 0; lt < 8; ++lt) {
      const int l = t * 256 + wl * 128 + lt * 16 + fl;
      if (l < LOUT) {
        float* zrow = Z + ((size_t)n * LOUT + l) * U_ + u0 + wu * 64 + ug;
#pragma unroll
        for (int ut = 0; ut < 4; ++ut) {
          f32x4 v = acc[ut][lt];
          *(f32x4*)(zrow + ut * 16) = v;
#pragma unroll
          for (int r = 0; r < 4; ++r) pmax[ut][r] = fmaxf(pmax[ut][r], v[r]);
        }
      }
    }

    // certify only the X stage (stage loads are OLDER than the 32 stores:
    // outstanding <= 32 implies all stage loads retired); stores in flight.
    if (t < 3) {
      asm volatile("s_waitcnt vmcnt(32)" ::: "memory");
      __builtin_amdgcn_s_barrier();
    }
  }

  // ---- S epilogue: reduce over the frag's 16 cols (fl), atomics once.
#pragma unroll
  for (int off = 1; off < 16; off <<= 1)
#pragma unroll
    for (int ut = 0; ut < 4; ++ut)
#pragma unroll
      for (int r = 0; r < 4; ++r)
        pmax[ut][r] = fmaxf(pmax[ut][r], __shfl_xor(pmax[ut][r], off));

  if (fl == 0) {                       // lanes fj*16
    const int tn = n / F_;
    float* Sp = out + (size_t)tn * U_ + u0 + wu * 64 + ug;
#pragma unroll
    for (int ut = 0; ut < 4; ++ut)
#pragma unroll
      for (int r = 0; r < 4; ++r)
        atomicMaxF(Sp + ut * 16 + r, pmax[ut][r]);
  }
}

extern "C" void kernel_launch(void* const* d_in, const int* in_sizes, int n_in,
                              void* d_out, int out_size, void* d_ws, size_t ws_size,
                              hipStream_t stream) {
  const float* X       = (const float*)d_in[0];
  const float* P_logit = (const float*)d_in[1];
  const float* Q       = (const float*)d_in[2];
  float* out = (float*)d_out;

  unsigned short* Rt = (unsigned short*)d_ws;            // 240 KB
  unsigned short* Xp = (unsigned short*)((char*)d_ws + 262144);
  // Xp: NIMG*XROWS*24 shorts (~18.6 MB). Last image/tile stages over-read
  // <= 1 KB past Xp into ws slack (poison = finite bf16; affected rows only
  // feed l >= LOUT outputs, which are guarded and never stored).

  int xthreads = NIMG * XROWS * 12;
  hipLaunchKernelGGL(xprep_kernel, dim3((xthreads + 255) / 256), dim3(256),
                     0, stream, X, P_logit, Q, out, Rt, (unsigned int*)Xp);
  dim3 grid(2, 1, NIMG);   // u-tiles, -, images (4 l-tiles looped in-kernel)
  hipLaunchKernelGGL(conv_kernel, grid, dim3(256), 0, stream, Xp, Rt, out);
}